// Round 5
// baseline (17662.877 us; speedup 1.0000x reference)
//
#include <hip/hip_runtime.h>
#include <hip/hip_bf16.h>
#include <cstdint>
#include <cstddef>

// BiLSTM-CRF forward + Viterbi decode, T=4096, E=300, H2=256, K=32.
//   K1 zx_gemm    : zx[t] = Wih @ embed[token] + b (both dirs, batched)
//   K2 lstm_kernel: one CU per direction. Whh f16: 6/8 rows in 192 regs,
//                   o-gate rows streamed from LDS at stride 69 dwords
//                   (69 mod 32 = 5, odd -> 2 lanes/bank = free; R4's 68 was
//                   4 mod 32 -> 8-way conflict, 2.1M SQ_LDS_BANK_CONFLICT).
//   K3 feat_kernel: feats = [hf|hb] @ W_out^T + b_out (h history bf16)
//   Viterbi, parallelized by max-plus associativity (reassociation = ulp
//   fv shifts = tie flips only; tags<=31 vs threshold ~222 -> safe):
//   K4a vit_phaseA: 128 chunk transfer matrices C_c (32x32 max-plus), parallel
//   K4b vit_phaseB: sequential 128-chunk matrix-vector pass (1 wave) -> fvs,
//                   terminal score/best
//   K4c vit_phaseC: per-chunk bptr regeneration from fvs (128 waves, parallel)
//   K5 compose, K6 backtrace: unchanged.

#define T_LEN 4096
#define E_DIM 300
#define H2 256
#define G4 1024
#define KTAGS 32
#define START_TAG 30
#define STOP_TAG 31
#define NEGV (-10000.0f)
#define NCHUNK 128
#define CLEN 32

typedef _Float16 h2_t __attribute__((ext_vector_type(2)));

__device__ __forceinline__ float fast_sigmoid(float x) {
  return __builtin_amdgcn_rcpf(1.0f + __expf(-x));
}
__device__ __forceinline__ float fast_tanh(float x) {
  return 1.0f - 2.0f * __builtin_amdgcn_rcpf(__expf(2.0f * x) + 1.0f);
}

template <int CTRL>
__device__ __forceinline__ float quad_add(float x) {
  int v = __builtin_amdgcn_update_dpp(0, __float_as_int(x), CTRL, 0xF, 0xF, true);
  return x + __int_as_float(v);
}

__device__ __forceinline__ int pk16(float a, float b) {
  return __builtin_bit_cast(int, __builtin_amdgcn_cvt_pkrtz(a, b));
}

__device__ __forceinline__ uint32_t pack_bf16(float a, float b) {
  uint32_t ua = __float_as_uint(a), ub = __float_as_uint(b);
  ua = (ua + 0x7FFFu + ((ua >> 16) & 1u)) >> 16;
  ub = (ub + 0x7FFFu + ((ub >> 16) & 1u)) & 0xFFFF0000u;
  return ua | ub;
}

// ---------------- K1: input projection GEMM ----------------
__global__ __launch_bounds__(256) void zx_gemm(
    const int* __restrict__ sent, const float* __restrict__ embed,
    const float* __restrict__ Wih_f, const float* __restrict__ b_f,
    const float* __restrict__ Wih_b, const float* __restrict__ b_b,
    float* __restrict__ zxF, float* __restrict__ zxB)
{
  const int dir = blockIdx.y;
  const int t0 = blockIdx.x * 8;
  const float* __restrict__ Wih = dir ? Wih_b : Wih_f;
  const float* __restrict__ bias = dir ? b_b : b_f;
  float* __restrict__ zx = dir ? zxB : zxF;

  __shared__ __align__(16) float xs[8 * E_DIM];
  const int tid = threadIdx.x;
  for (int ti = 0; ti < 8; ++ti) {
    int p = t0 + ti;
    int tok = sent[dir ? (T_LEN - 1 - p) : p];
    const float* er = embed + (size_t)tok * E_DIM;
    for (int k = tid; k < E_DIM; k += 256) xs[ti * E_DIM + k] = er[k];
  }
  __syncthreads();

  const int r = tid;
  float acc[4][8];
#pragma unroll
  for (int g = 0; g < 4; ++g) {
    float bv = bias[g * 256 + r];
#pragma unroll
    for (int ti = 0; ti < 8; ++ti) acc[g][ti] = bv;
  }
  const float4* w0p = (const float4*)(Wih + (size_t)(r) * E_DIM);
  const float4* w1p = (const float4*)(Wih + (size_t)(256 + r) * E_DIM);
  const float4* w2p = (const float4*)(Wih + (size_t)(512 + r) * E_DIM);
  const float4* w3p = (const float4*)(Wih + (size_t)(768 + r) * E_DIM);
  for (int k4 = 0; k4 < E_DIM / 4; ++k4) {
    float4 w0 = w0p[k4], w1 = w1p[k4], w2 = w2p[k4], w3 = w3p[k4];
#pragma unroll
    for (int ti = 0; ti < 8; ++ti) {
      float4 x4 = *(const float4*)(xs + ti * E_DIM + k4 * 4);
      acc[0][ti] += w0.x * x4.x + w0.y * x4.y + w0.z * x4.z + w0.w * x4.w;
      acc[1][ti] += w1.x * x4.x + w1.y * x4.y + w1.z * x4.z + w1.w * x4.w;
      acc[2][ti] += w2.x * x4.x + w2.y * x4.y + w2.z * x4.z + w2.w * x4.w;
      acc[3][ti] += w3.x * x4.x + w3.y * x4.y + w3.z * x4.z + w3.w * x4.w;
    }
  }
#pragma unroll
  for (int g = 0; g < 4; ++g)
#pragma unroll
    for (int ti = 0; ti < 8; ++ti)
      zx[(size_t)(t0 + ti) * G4 + g * 256 + r] = acc[g][ti];
}

// ---------------- K2: single-CU-per-direction LSTM ----------------
__global__ __launch_bounds__(512, 2) void lstm_kernel(
    const float* __restrict__ Whh_f, const float* __restrict__ Whh_b,
    const float* __restrict__ h0, const float* __restrict__ c0,
    const float* __restrict__ zxF, const float* __restrict__ zxB,
    uint32_t* __restrict__ hhF32, uint32_t* __restrict__ hhB32)
{
  const int d = blockIdx.x;
  const float* __restrict__ Whh = d ? Whh_b : Whh_f;
  const float* __restrict__ zxd = d ? zxB : zxF;
  uint32_t* __restrict__ hh32 = d ? hhB32 : hhF32;

  const int tid = threadIdx.x;
  const int kpart = tid & 3;
  const int q = tid >> 2;
  const int k0 = kpart * 64;

  // stride 69 dwords: 69 mod 32 = 5 (odd) -> lanes t,t+32 share a bank only
  // (2-way = free); R4's 68 gave 4 mod 32 -> 8-way.
  __shared__ int wlds[512 * 69];            // 141.3 KB
  __shared__ __align__(16) int hA[128];
  __shared__ __align__(16) int hB[128];

  int wreg[192];
#pragma unroll
  for (int m = 0; m < 6; ++m) {
    int g = m >> 1, e = m & 1;
    const float4* wp = (const float4*)(Whh + (size_t)(g * 256 + 2 * q + e) * H2 + k0);
#pragma unroll
    for (int i = 0; i < 16; ++i) {
      float4 v = wp[i];
      wreg[m * 32 + i * 2] = pk16(v.x, v.y);
      wreg[m * 32 + i * 2 + 1] = pk16(v.z, v.w);
    }
  }
  {
    int* wl = wlds + tid * 69;
    for (int e = 0; e < 2; ++e) {
      const float4* wp = (const float4*)(Whh + (size_t)(3 * 256 + 2 * q + e) * H2 + k0);
#pragma unroll
      for (int i = 0; i < 16; ++i) {
        float4 v = wp[i];
        wl[e * 32 + i * 2] = pk16(v.x, v.y);
        wl[e * 32 + i * 2 + 1] = pk16(v.z, v.w);
      }
    }
  }

  float c0r = c0[d * H2 + 2 * q];
  float c1r = c0[d * H2 + 2 * q + 1];
  if (tid < 128) hA[tid] = pk16(h0[d * H2 + 2 * tid], h0[d * H2 + 2 * tid + 1]);
  __syncthreads();

  const float* zp = zxd + 2 * q;
  uint32_t* hp = hh32 + q;
  const int* wl = wlds + tid * 69;

  auto step = [&](const int* hin, int* hout) {
    float2 zi2 = *(const float2*)(zp);
    float2 zf2 = *(const float2*)(zp + 256);
    float2 zg2 = *(const float2*)(zp + 512);
    float2 zo2 = *(const float2*)(zp + 768);

    // all h chunks up-front: 8 b128 broadcast reads (16-lane same-address)
    int h8[32];
#pragma unroll
    for (int i = 0; i < 8; ++i)
      *(int4*)(h8 + 4 * i) = *(const int4*)(hin + kpart * 32 + 4 * i);

    float acc[8] = {0.f, 0.f, 0.f, 0.f, 0.f, 0.f, 0.f, 0.f};
#pragma unroll
    for (int cc = 0; cc < 4; ++cc) {
      int w6[8], w7[8];
      *(int4*)(w6) = *(const int4*)(wl + cc * 8);
      *(int4*)(w6 + 4) = *(const int4*)(wl + cc * 8 + 4);
      *(int4*)(w7) = *(const int4*)(wl + 32 + cc * 8);
      *(int4*)(w7 + 4) = *(const int4*)(wl + 32 + cc * 8 + 4);
#pragma unroll
      for (int j = 0; j < 8; ++j) {
        h2_t hv = __builtin_bit_cast(h2_t, h8[cc * 8 + j]);
        acc[0] = __builtin_amdgcn_fdot2(__builtin_bit_cast(h2_t, wreg[0 * 32 + cc * 8 + j]), hv, acc[0], false);
        acc[1] = __builtin_amdgcn_fdot2(__builtin_bit_cast(h2_t, wreg[1 * 32 + cc * 8 + j]), hv, acc[1], false);
        acc[2] = __builtin_amdgcn_fdot2(__builtin_bit_cast(h2_t, wreg[2 * 32 + cc * 8 + j]), hv, acc[2], false);
        acc[3] = __builtin_amdgcn_fdot2(__builtin_bit_cast(h2_t, wreg[3 * 32 + cc * 8 + j]), hv, acc[3], false);
        acc[4] = __builtin_amdgcn_fdot2(__builtin_bit_cast(h2_t, wreg[4 * 32 + cc * 8 + j]), hv, acc[4], false);
        acc[5] = __builtin_amdgcn_fdot2(__builtin_bit_cast(h2_t, wreg[5 * 32 + cc * 8 + j]), hv, acc[5], false);
        acc[6] = __builtin_amdgcn_fdot2(__builtin_bit_cast(h2_t, w6[j]), hv, acc[6], false);
        acc[7] = __builtin_amdgcn_fdot2(__builtin_bit_cast(h2_t, w7[j]), hv, acc[7], false);
      }
    }
#pragma unroll
    for (int m = 0; m < 8; ++m) {
      acc[m] = quad_add<0xB1>(acc[m]);
      acc[m] = quad_add<0x4E>(acc[m]);
    }
    float zi0 = acc[0] + zi2.x, zi1 = acc[1] + zi2.y;
    float zf0 = acc[2] + zf2.x, zf1 = acc[3] + zf2.y;
    float zg0 = acc[4] + zg2.x, zg1 = acc[5] + zg2.y;
    float zo0 = acc[6] + zo2.x, zo1 = acc[7] + zo2.y;
    c0r = fast_sigmoid(zf0) * c0r + fast_sigmoid(zi0) * fast_tanh(zg0);
    c1r = fast_sigmoid(zf1) * c1r + fast_sigmoid(zi1) * fast_tanh(zg1);
    float hv0 = fast_sigmoid(zo0) * fast_tanh(c0r);
    float hv1 = fast_sigmoid(zo1) * fast_tanh(c1r);
    if (kpart == 0) {
      hout[q] = pk16(hv0, hv1);
      *hp = pack_bf16(hv0, hv1);
    }
    zp += G4;
    hp += 128;
    __syncthreads();
  };

  for (int t = 0; t < T_LEN; t += 2) {
    step(hA, hB);
    step(hB, hA);
  }
}

// ---------------- K3: feats = [hf|hb] @ W_out^T + b_out ----------------
__global__ __launch_bounds__(256) void feat_kernel(
    const __hip_bfloat16* __restrict__ hhF, const __hip_bfloat16* __restrict__ hhB,
    const float* __restrict__ W_out, const float* __restrict__ b_out,
    float* __restrict__ feats)
{
  const int p0 = blockIdx.x * 8;
  const int tid = threadIdx.x;
  __shared__ float hs[8 * 520];
#define HIDX(pos, k) ((pos) * 520 + (k) + ((k) >> 6))
  for (int idx = tid; idx < 2048; idx += 256) {
    int pos = idx >> 8, k = idx & 255;
    hs[HIDX(pos, k)] = (float)hhF[(size_t)(p0 + pos) * H2 + k];
    hs[HIDX(pos, 256 + k)] = (float)hhB[(size_t)(T_LEN - 1 - (p0 + pos)) * H2 + k];
  }
  __syncthreads();

  const int tag = tid >> 3;
  const int kc = tid & 7;
  float4 w4[16];
  const float4* wp = (const float4*)(W_out + tag * 512 + kc * 64);
#pragma unroll
  for (int i = 0; i < 16; ++i) w4[i] = wp[i];
  const float bo = b_out[tag];

#pragma unroll
  for (int pos = 0; pos < 8; ++pos) {
    const float* hpp = hs + pos * 520 + kc * 64 + kc;
    float a = 0.f;
#pragma unroll
    for (int i = 0; i < 16; ++i) {
      float4 w = w4[i];
      a += w.x * hpp[i * 4] + w.y * hpp[i * 4 + 1] + w.z * hpp[i * 4 + 2] + w.w * hpp[i * 4 + 3];
    }
    a += __shfl_xor(a, 1);
    a += __shfl_xor(a, 2);
    a += __shfl_xor(a, 4);
    if (kc == 0) feats[(size_t)(p0 + pos) * KTAGS + tag] = a + bo;
  }
}

// ---------------- K4a: parallel chunk transfer matrices ----------------
// C_c = M_{t0+31} (x) ... (x) M_{t0},  M_t[i][j] = T[i][j] + feat[t][i]
// thread (i,j); T-row in regs; C double-buffered in LDS. Max is exact;
// add reassociation vs sequential scan is ulp-level (tie flips only).
__global__ __launch_bounds__(1024) void vit_phaseA(
    const float* __restrict__ feats, const float* __restrict__ trans,
    float* __restrict__ Cmat)
{
  const int c = blockIdx.x;
  const int tid = threadIdx.x;
  const int i = tid >> 5, j = tid & 31;
  const int t0 = c * CLEN;

  float Trow[32];
#pragma unroll
  for (int k = 0; k < 32; ++k) Trow[k] = trans[i * 32 + k];

  __shared__ float Ca[1024], Cb[1024];
  Ca[tid] = Trow[j] + feats[(size_t)t0 * KTAGS + i];
  __syncthreads();

  float* cur = Ca;
  float* nxt = Cb;
  for (int s = 1; s < CLEN; ++s) {
    float fi = feats[(size_t)(t0 + s) * KTAGS + i];
    float m = Trow[0] + cur[j];
#pragma unroll
    for (int k = 1; k < 32; ++k) m = fmaxf(m, Trow[k] + cur[k * 32 + j]);
    nxt[tid] = m + fi;
    __syncthreads();
    float* tmp = cur; cur = nxt; nxt = tmp;
  }
  Cmat[(size_t)c * 1024 + tid] = cur[tid];
}

// ---------------- K4b: sequential chunk-level pass (tiny) ----------------
__global__ __launch_bounds__(64) void vit_phaseB(
    const float* __restrict__ Cmat, const float* __restrict__ trans,
    float* __restrict__ fvs, float* __restrict__ score_out,
    int* __restrict__ best_out)
{
  const int ln = threadIdx.x;
  const int i = ln & 31;
  float fv = (i == START_TAG) ? 0.0f : NEGV;
  if (ln < 32) fvs[i] = fv;

  for (int c = 0; c < NCHUNK; ++c) {
    const float* Crow = Cmat + (size_t)c * 1024 + i * 32;
    float cr[32];
#pragma unroll
    for (int w = 0; w < 8; ++w) *(float4*)(cr + 4 * w) = *(const float4*)(Crow + 4 * w);
    float m = cr[0] + __shfl(fv, 0);
#pragma unroll
    for (int jj = 1; jj < 32; ++jj) m = fmaxf(m, cr[jj] + __shfl(fv, jj));
    fv = m;
    if (ln < 32) fvs[(c + 1) * 32 + i] = fv;
  }

  float v = fv + trans[STOP_TAG * 32 + i];
  int bi = i;
#pragma unroll
  for (int m = 1; m < 32; m <<= 1) {
    float ov = __shfl_xor(v, m);
    int oi = __shfl_xor(bi, m);
    if (ov > v || (ov == v && oi < bi)) { v = ov; bi = oi; }
  }
  if (ln == 0) { score_out[0] = v; best_out[0] = bi; }
}

// ---------------- K4c: parallel per-chunk bptr regeneration ----------------
__global__ __launch_bounds__(64) void vit_phaseC(
    const float* __restrict__ feats, const float* __restrict__ trans,
    const float* __restrict__ fvs, unsigned char* __restrict__ bptr)
{
  const int c = blockIdx.x;
  const int ln = threadIdx.x;
  const int i = ln & 31;
  const int jb = ln >> 5;
  const int t0 = c * CLEN;

  float Tj[16];
#pragma unroll
  for (int s = 0; s < 16; ++s) Tj[s] = trans[i * 32 + jb * 16 + s];

  float fv = fvs[c * 32 + i];
  float pf = feats[(size_t)t0 * KTAGS + i];

  for (int s = 0; s < CLEN; ++s) {
    float cv[16];
    int cj[16];
#pragma unroll
    for (int ss = 0; ss < 16; ++ss) {
      cv[ss] = __shfl(fv, jb * 16 + ss) + Tj[ss];
      cj[ss] = jb * 16 + ss;
    }
#pragma unroll
    for (int st = 1; st < 16; st <<= 1)
#pragma unroll
      for (int ss = 0; ss < 16; ss += 2 * st)
        if (cv[ss + st] > cv[ss]) { cv[ss] = cv[ss + st]; cj[ss] = cj[ss + st]; }
    float v = cv[0];
    int bj = cj[0];
    float ov = __shfl_xor(v, 32);
    int oj = __shfl_xor(bj, 32);
    if (ov > v || (ov == v && oj < bj)) { v = ov; bj = oj; }

    int t = t0 + s;
    float f = pf;
    int tn = (t + 1 < T_LEN) ? t + 1 : t;
    pf = feats[(size_t)tn * KTAGS + i];
    fv = v + f;
    if (jb == 0) bptr[(size_t)t * KTAGS + i] = (unsigned char)bj;
  }
}

// ---------------- K5: compose 32-step backtrace maps ----------------
__global__ __launch_bounds__(64) void vit_compose(
    const unsigned char* __restrict__ bptr, unsigned char* __restrict__ fmap)
{
  const int m = blockIdx.x;
  __shared__ unsigned char B[32 * 32];
  const int tid = threadIdx.x;
  const uint32_t* src = (const uint32_t*)(bptr + (size_t)m * 1024);
  uint32_t* dstw = (uint32_t*)B;
  for (int idx = tid; idx < 256; idx += 64) dstw[idx] = src[idx];
  __syncthreads();
  if (tid < 32) {
    int y = tid;
#pragma unroll
    for (int tt = 31; tt >= 0; --tt) y = B[tt * 32 + y];
    fmap[m * 32 + tid] = (unsigned char)y;
  }
}

// ---------------- K6: boundary walk + parallel expansion ----------------
__global__ __launch_bounds__(256) void vit_backtrace(
    const unsigned char* __restrict__ bptr, const unsigned char* __restrict__ fmap,
    const int* __restrict__ best, float* __restrict__ path_out)
{
  __shared__ unsigned char F[128 * 32];
  __shared__ unsigned char bound[128];
  const int tid = threadIdx.x;
  const uint32_t* src = (const uint32_t*)fmap;
  uint32_t* dstw = (uint32_t*)F;
  for (int idx = tid; idx < 1024; idx += 256) dstw[idx] = src[idx];
  __syncthreads();
  if (tid == 0) {
    int y = best[0];
    bound[127] = (unsigned char)y;
    for (int m = 127; m >= 1; --m) {
      y = F[m * 32 + y];
      bound[m - 1] = (unsigned char)y;
    }
  }
  __syncthreads();
  if (tid < 128) {
    const int m = tid;
    int y = bound[m];
    path_out[m * 32 + 31] = (float)y;
    for (int tt = 30; tt >= 0; --tt) {
      y = bptr[(size_t)(m * 32 + tt + 1) * 32 + y];
      path_out[m * 32 + tt] = (float)y;
    }
  }
}

extern "C" void kernel_launch(void* const* d_in, const int* in_sizes, int n_in,
                              void* d_out, int out_size, void* d_ws, size_t ws_size,
                              hipStream_t stream)
{
  const int* sent    = (const int*)d_in[0];
  const float* embed = (const float*)d_in[1];
  const float* Wih_f = (const float*)d_in[2];
  const float* Whh_f = (const float*)d_in[3];
  const float* b_f   = (const float*)d_in[4];
  const float* Wih_b = (const float*)d_in[5];
  const float* Whh_b = (const float*)d_in[6];
  const float* b_b   = (const float*)d_in[7];
  const float* W_out = (const float*)d_in[8];
  const float* b_out = (const float*)d_in[9];
  const float* trans = (const float*)d_in[10];
  const float* h0    = (const float*)d_in[11];
  const float* c0    = (const float*)d_in[12];

  float* W = (float*)d_ws;
  float* zxF = W;                                    // 16 MB (dead after lstm)
  float* zxB = zxF + (size_t)T_LEN * G4;             // 16 MB
  float* feats = zxB + (size_t)T_LEN * G4;           // 512 KB
  uint32_t* hhF32 = (uint32_t*)(feats + (size_t)T_LEN * KTAGS);  // 2 MB
  uint32_t* hhB32 = hhF32 + (size_t)T_LEN * 128;     // 2 MB
  int* bestIdx = (int*)(hhB32 + (size_t)T_LEN * 128);
  unsigned char* bptr = (unsigned char*)(bestIdx + 16);  // 128 KB
  unsigned char* fmap = bptr + (size_t)T_LEN * KTAGS;    // 4 KB
  // overlay on dead zxF region: chunk matrices + chunk-boundary fv vectors
  float* Cmat = zxF;                                 // 128*1024 floats = 512 KB
  float* fvs = zxF + NCHUNK * 1024;                  // 129*32 floats

  float* out = (float*)d_out;  // out[0]=path_score, out[1..4096]=path tags

  zx_gemm<<<dim3(T_LEN / 8, 2), 256, 0, stream>>>(sent, embed, Wih_f, b_f, Wih_b, b_b, zxF, zxB);
  lstm_kernel<<<2, 512, 0, stream>>>(Whh_f, Whh_b, h0, c0, zxF, zxB, hhF32, hhB32);
  feat_kernel<<<T_LEN / 8, 256, 0, stream>>>((const __hip_bfloat16*)hhF32,
                                             (const __hip_bfloat16*)hhB32,
                                             W_out, b_out, feats);
  vit_phaseA<<<NCHUNK, 1024, 0, stream>>>(feats, trans, Cmat);
  vit_phaseB<<<1, 64, 0, stream>>>(Cmat, trans, fvs, out, bestIdx);
  vit_phaseC<<<NCHUNK, 64, 0, stream>>>(feats, trans, fvs, bptr);
  vit_compose<<<128, 64, 0, stream>>>(bptr, fmap);
  vit_backtrace<<<1, 256, 0, stream>>>(bptr, fmap, bestIdx, out + 1);
}

// Round 6
// 4826.312 us; speedup vs baseline: 3.6597x; 3.6597x over previous
//
#include <hip/hip_runtime.h>
#include <hip/hip_bf16.h>
#include <cstdint>
#include <cstddef>

// BiLSTM-CRF forward + Viterbi decode, T=4096, E=300, H2=256, K=32.
//   K1 zx_gemm    : zx[t] = Wih @ embed[token] + b (both dirs, batched)
//   K2 lstm_kernel: one CU per direction, 1024 thr. INT8 weight-stationary:
//                   each thread owns ONE gate-row (64 int8x4 dwords, per-row
//                   scale) -> all of Whh in arch VGPRs, no LDS weight stream
//                   (R4's o-gate LDS stream was 1024 cy/step; R5's stride-69
//                   "fix" broke b128 alignment -> 2.3x regression). Quad
//                   lanes 4e..4e+3 = gates i,f,g,o of elem e; z-combine = 3
//                   quad-perm DPPs; h broadcast-read from LDS (256 B/step).
//                   Custom barrier (s_waitcnt lgkmcnt(0); s_barrier) skips
//                   the compiler's vmcnt(0) drain so zx prefetch crosses
//                   steps. h history stored int8 (scale 1/127).
//   K3 feat_kernel: feats = [hf|hb] @ W_out^T + b_out (unpack int8 h)
//   K4a/b/c       : Viterbi via max-plus chunk composition (R5, worked:
//                   non-lstm 2.76 -> 0.66 ms)
//   K5 compose, K6 backtrace: parallel backtrace reconstruction.

#define T_LEN 4096
#define E_DIM 300
#define H2 256
#define G4 1024
#define KTAGS 32
#define START_TAG 30
#define STOP_TAG 31
#define NEGV (-10000.0f)
#define NCHUNK 128
#define CLEN 32

#if defined(__has_builtin)
#if __has_builtin(__builtin_amdgcn_sdot4)
#define HAVE_SDOT4 1
#endif
#endif
#ifndef HAVE_SDOT4
#define HAVE_SDOT4 0
#endif

__device__ __forceinline__ int dot4(int a, int b, int c) {
#if HAVE_SDOT4
  return __builtin_amdgcn_sdot4(a, b, c, false);
#else
  int r = c;
  r += (int)(int8_t)(a) * (int)(int8_t)(b);
  r += (int)(int8_t)(a >> 8) * (int)(int8_t)(b >> 8);
  r += (int)(int8_t)(a >> 16) * (int)(int8_t)(b >> 16);
  r += (int)(int8_t)(a >> 24) * (int)(int8_t)(b >> 24);
  return r;
#endif
}

__device__ __forceinline__ float fast_sigmoid(float x) {
  return __builtin_amdgcn_rcpf(1.0f + __expf(-x));
}
__device__ __forceinline__ float fast_tanh(float x) {
  return 1.0f - 2.0f * __builtin_amdgcn_rcpf(__expf(2.0f * x) + 1.0f);
}

template <int CTRL>
__device__ __forceinline__ float dppmov(float x) {
  // quad_perm lane permutation (VALU pipe)
  return __int_as_float(
      __builtin_amdgcn_update_dpp(0, __float_as_int(x), CTRL, 0xF, 0xF, true));
}

// ---------------- K1: input projection GEMM ----------------
__global__ __launch_bounds__(256) void zx_gemm(
    const int* __restrict__ sent, const float* __restrict__ embed,
    const float* __restrict__ Wih_f, const float* __restrict__ b_f,
    const float* __restrict__ Wih_b, const float* __restrict__ b_b,
    float* __restrict__ zxF, float* __restrict__ zxB)
{
  const int dir = blockIdx.y;
  const int t0 = blockIdx.x * 8;
  const float* __restrict__ Wih = dir ? Wih_b : Wih_f;
  const float* __restrict__ bias = dir ? b_b : b_f;
  float* __restrict__ zx = dir ? zxB : zxF;

  __shared__ __align__(16) float xs[8 * E_DIM];
  const int tid = threadIdx.x;
  for (int ti = 0; ti < 8; ++ti) {
    int p = t0 + ti;
    int tok = sent[dir ? (T_LEN - 1 - p) : p];
    const float* er = embed + (size_t)tok * E_DIM;
    for (int k = tid; k < E_DIM; k += 256) xs[ti * E_DIM + k] = er[k];
  }
  __syncthreads();

  const int r = tid;
  float acc[4][8];
#pragma unroll
  for (int g = 0; g < 4; ++g) {
    float bv = bias[g * 256 + r];
#pragma unroll
    for (int ti = 0; ti < 8; ++ti) acc[g][ti] = bv;
  }
  const float4* w0p = (const float4*)(Wih + (size_t)(r) * E_DIM);
  const float4* w1p = (const float4*)(Wih + (size_t)(256 + r) * E_DIM);
  const float4* w2p = (const float4*)(Wih + (size_t)(512 + r) * E_DIM);
  const float4* w3p = (const float4*)(Wih + (size_t)(768 + r) * E_DIM);
  for (int k4 = 0; k4 < E_DIM / 4; ++k4) {
    float4 w0 = w0p[k4], w1 = w1p[k4], w2 = w2p[k4], w3 = w3p[k4];
#pragma unroll
    for (int ti = 0; ti < 8; ++ti) {
      float4 x4 = *(const float4*)(xs + ti * E_DIM + k4 * 4);
      acc[0][ti] += w0.x * x4.x + w0.y * x4.y + w0.z * x4.z + w0.w * x4.w;
      acc[1][ti] += w1.x * x4.x + w1.y * x4.y + w1.z * x4.z + w1.w * x4.w;
      acc[2][ti] += w2.x * x4.x + w2.y * x4.y + w2.z * x4.z + w2.w * x4.w;
      acc[3][ti] += w3.x * x4.x + w3.y * x4.y + w3.z * x4.z + w3.w * x4.w;
    }
  }
#pragma unroll
  for (int g = 0; g < 4; ++g)
#pragma unroll
    for (int ti = 0; ti < 8; ++ti)
      zx[(size_t)(t0 + ti) * G4 + g * 256 + r] = acc[g][ti];
}

// ---------------- K2: int8 weight-stationary LSTM ----------------
__global__ __launch_bounds__(1024, 4) void lstm_kernel(
    const float* __restrict__ Whh_f, const float* __restrict__ Whh_b,
    const float* __restrict__ h0, const float* __restrict__ c0,
    const float* __restrict__ zxF, const float* __restrict__ zxB,
    uint32_t* __restrict__ hhF, uint32_t* __restrict__ hhB)
{
  const int d = blockIdx.x;
  const float* __restrict__ Whh = d ? Whh_b : Whh_f;
  const float* __restrict__ zxd = d ? zxB : zxF;
  uint32_t* __restrict__ hh = d ? hhB : hhF;

  const int tid = threadIdx.x;
  const int g = tid & 3;        // gate (i,f,g,o) — lane&3 within quad
  const int e = tid >> 2;       // h element 0..255
  const int row = g * 256 + e;  // gate-row (matches zx layout)

  __shared__ __align__(16) uint32_t hQA[64];  // int8-packed h, 256 B
  __shared__ __align__(16) uint32_t hQB[64];

  // ---- one-time: quantize my gate-row to int8, per-row scale ----
  const float4* Wr = (const float4*)(Whh + (size_t)row * H2);
  float amax = 0.f;
  for (int i = 0; i < 64; ++i) {
    float4 v = Wr[i];
    amax = fmaxf(amax, fmaxf(fmaxf(fabsf(v.x), fabsf(v.y)),
                             fmaxf(fabsf(v.z), fabsf(v.w))));
  }
  const float winv = (amax > 0.f) ? 127.f / amax : 0.f;
  const float sw = amax / 127.f;
  int wq[64];
  for (int i = 0; i < 64; ++i) {
    float4 v = Wr[i];
    int b0 = ((int)rintf(v.x * winv)) & 255;
    int b1 = ((int)rintf(v.y * winv)) & 255;
    int b2 = ((int)rintf(v.z * winv)) & 255;
    int b3 = ((int)rintf(v.w * winv)) & 255;
    wq[i] = b0 | (b1 << 8) | (b2 << 16) | (b3 << 24);
  }

  // ---- h0 scale (h0 ~ N(0,1), unbounded; computed redundantly) ----
  float h0max = 1e-12f;
  const float4* H0 = (const float4*)(h0 + d * H2);
  for (int i = 0; i < 64; ++i) {
    float4 v = H0[i];
    h0max = fmaxf(h0max, fmaxf(fmaxf(fabsf(v.x), fabsf(v.y)),
                               fmaxf(fabsf(v.z), fabsf(v.w))));
  }
  float sh = h0max / 127.f;  // scale of h currently in the live buffer
  if (tid < 64) {
    float inv0 = 127.f / h0max;
    float4 v = H0[tid];
    int b0 = ((int)rintf(v.x * inv0)) & 255;
    int b1 = ((int)rintf(v.y * inv0)) & 255;
    int b2 = ((int)rintf(v.z * inv0)) & 255;
    int b3 = ((int)rintf(v.w * inv0)) & 255;
    hQA[tid] = (uint32_t)(b0 | (b1 << 8) | (b2 << 16) | (b3 << 24));
  }

  float c = (g == 0) ? c0[d * H2 + e] : 0.f;  // c lives in the i-gate lane

  const float* zp = zxd + row;
  float zcur = zp[0];  // zx for t=0
  __syncthreads();

  auto step = [&](const uint32_t* hin, uint32_t* hout, int t) {
    // prefetch zx for t+1 — custom barrier below keeps it in flight
    float znext = (t + 1 < T_LEN) ? zp[(size_t)(t + 1) * G4] : 0.f;

    // matvec: 64 sdot4 over the broadcast h buffer
    int acc = 0;
#pragma unroll
    for (int ch = 0; ch < 8; ++ch) {
      uint32_t hd[8];
      *(uint4*)(hd) = *((const uint4*)hin + ch * 2);
      *(uint4*)(hd + 4) = *((const uint4*)hin + ch * 2 + 1);
#pragma unroll
      for (int j = 0; j < 8; ++j) acc = dot4(wq[ch * 8 + j], hd[j], acc);
    }
    float z = (float)acc * (sw * sh) + zcur;

    // gather all 4 gate-z's into the i-gate lane (3 quad-perm DPPs)
    float p1 = dppmov<0xB1>(z);  // lane^1
    float p2 = dppmov<0x4E>(z);  // lane^2
    float p3 = dppmov<0x1B>(z);  // lane^3
    if (g == 0) {
      // lane0 of quad: z=zi, p1=zf, p2=zg, p3=zo
      c = fast_sigmoid(p1) * c + fast_sigmoid(z) * fast_tanh(p2);
      float hv = fast_sigmoid(p3) * fast_tanh(c);
      int q = (int)rintf(hv * 127.f);  // |hv|<1 -> fits int8
      ((unsigned char*)hout)[e] = (unsigned char)q;
    }
    zcur = znext;
    // barrier WITHOUT vmcnt drain: LDS producer/consumer ordering only
    asm volatile("s_waitcnt lgkmcnt(0)\n\ts_barrier" ::: "memory");
    if (tid < 64) hh[(size_t)t * 64 + tid] = hout[tid];  // int8 h history
    sh = 1.f / 127.f;  // buffers hold tanh-bounded h from now on
  };

  for (int t = 0; t < T_LEN; t += 2) {
    step(hQA, hQB, t);
    step(hQB, hQA, t + 1);
  }
}

// ---------------- K3: feats = [hf|hb] @ W_out^T + b_out ----------------
__global__ __launch_bounds__(256) void feat_kernel(
    const uint32_t* __restrict__ hhF, const uint32_t* __restrict__ hhB,
    const float* __restrict__ W_out, const float* __restrict__ b_out,
    float* __restrict__ feats)
{
  const int p0 = blockIdx.x * 8;
  const int tid = threadIdx.x;
  __shared__ float hs[8 * 520];
#define HIDX(pos, k) ((pos) * 520 + (k) + ((k) >> 6))
  const float s = 1.f / 127.f;
  for (int idx = tid; idx < 512; idx += 256) {  // 8 pos x 64 dwords
    int pos = idx >> 6, dw = idx & 63;
    uint32_t vf = hhF[(size_t)(p0 + pos) * 64 + dw];
    uint32_t vb = hhB[(size_t)(T_LEN - 1 - (p0 + pos)) * 64 + dw];
    int k = dw * 4;
    hs[HIDX(pos, k + 0)] = (float)(int8_t)(vf) * s;
    hs[HIDX(pos, k + 1)] = (float)(int8_t)(vf >> 8) * s;
    hs[HIDX(pos, k + 2)] = (float)(int8_t)(vf >> 16) * s;
    hs[HIDX(pos, k + 3)] = (float)(int8_t)(vf >> 24) * s;
    int kb = 256 + k;
    hs[HIDX(pos, kb + 0)] = (float)(int8_t)(vb) * s;
    hs[HIDX(pos, kb + 1)] = (float)(int8_t)(vb >> 8) * s;
    hs[HIDX(pos, kb + 2)] = (float)(int8_t)(vb >> 16) * s;
    hs[HIDX(pos, kb + 3)] = (float)(int8_t)(vb >> 24) * s;
  }
  __syncthreads();

  const int tag = tid >> 3;
  const int kc = tid & 7;
  float4 w4[16];
  const float4* wp = (const float4*)(W_out + tag * 512 + kc * 64);
#pragma unroll
  for (int i = 0; i < 16; ++i) w4[i] = wp[i];
  const float bo = b_out[tag];

#pragma unroll
  for (int pos = 0; pos < 8; ++pos) {
    const float* hpp = hs + pos * 520 + kc * 64 + kc;
    float a = 0.f;
#pragma unroll
    for (int i = 0; i < 16; ++i) {
      float4 w = w4[i];
      a += w.x * hpp[i * 4] + w.y * hpp[i * 4 + 1] + w.z * hpp[i * 4 + 2] + w.w * hpp[i * 4 + 3];
    }
    a += __shfl_xor(a, 1);
    a += __shfl_xor(a, 2);
    a += __shfl_xor(a, 4);
    if (kc == 0) feats[(size_t)(p0 + pos) * KTAGS + tag] = a + bo;
  }
}

// ---------------- K4a: parallel chunk transfer matrices ----------------
__global__ __launch_bounds__(1024) void vit_phaseA(
    const float* __restrict__ feats, const float* __restrict__ trans,
    float* __restrict__ Cmat)
{
  const int c = blockIdx.x;
  const int tid = threadIdx.x;
  const int i = tid >> 5, j = tid & 31;
  const int t0 = c * CLEN;

  float Trow[32];
#pragma unroll
  for (int k = 0; k < 32; ++k) Trow[k] = trans[i * 32 + k];

  __shared__ float Ca[1024], Cb[1024];
  Ca[tid] = Trow[j] + feats[(size_t)t0 * KTAGS + i];
  __syncthreads();

  float* cur = Ca;
  float* nxt = Cb;
  for (int s = 1; s < CLEN; ++s) {
    float fi = feats[(size_t)(t0 + s) * KTAGS + i];
    float m = Trow[0] + cur[j];
#pragma unroll
    for (int k = 1; k < 32; ++k) m = fmaxf(m, Trow[k] + cur[k * 32 + j]);
    nxt[tid] = m + fi;
    __syncthreads();
    float* tmp = cur; cur = nxt; nxt = tmp;
  }
  Cmat[(size_t)c * 1024 + tid] = cur[tid];
}

// ---------------- K4b: sequential chunk-level pass (tiny) ----------------
__global__ __launch_bounds__(64) void vit_phaseB(
    const float* __restrict__ Cmat, const float* __restrict__ trans,
    float* __restrict__ fvs, float* __restrict__ score_out,
    int* __restrict__ best_out)
{
  const int ln = threadIdx.x;
  const int i = ln & 31;
  float fv = (i == START_TAG) ? 0.0f : NEGV;
  if (ln < 32) fvs[i] = fv;

  for (int c = 0; c < NCHUNK; ++c) {
    const float* Crow = Cmat + (size_t)c * 1024 + i * 32;
    float cr[32];
#pragma unroll
    for (int w = 0; w < 8; ++w) *(float4*)(cr + 4 * w) = *(const float4*)(Crow + 4 * w);
    float m = cr[0] + __shfl(fv, 0);
#pragma unroll
    for (int jj = 1; jj < 32; ++jj) m = fmaxf(m, cr[jj] + __shfl(fv, jj));
    fv = m;
    if (ln < 32) fvs[(c + 1) * 32 + i] = fv;
  }

  float v = fv + trans[STOP_TAG * 32 + i];
  int bi = i;
#pragma unroll
  for (int m = 1; m < 32; m <<= 1) {
    float ov = __shfl_xor(v, m);
    int oi = __shfl_xor(bi, m);
    if (ov > v || (ov == v && oi < bi)) { v = ov; bi = oi; }
  }
  if (ln == 0) { score_out[0] = v; best_out[0] = bi; }
}

// ---------------- K4c: parallel per-chunk bptr regeneration ----------------
__global__ __launch_bounds__(64) void vit_phaseC(
    const float* __restrict__ feats, const float* __restrict__ trans,
    const float* __restrict__ fvs, unsigned char* __restrict__ bptr)
{
  const int c = blockIdx.x;
  const int ln = threadIdx.x;
  const int i = ln & 31;
  const int jb = ln >> 5;
  const int t0 = c * CLEN;

  float Tj[16];
#pragma unroll
  for (int s = 0; s < 16; ++s) Tj[s] = trans[i * 32 + jb * 16 + s];

  float fv = fvs[c * 32 + i];
  float pf = feats[(size_t)t0 * KTAGS + i];

  for (int s = 0; s < CLEN; ++s) {
    float cv[16];
    int cj[16];
#pragma unroll
    for (int ss = 0; ss < 16; ++ss) {
      cv[ss] = __shfl(fv, jb * 16 + ss) + Tj[ss];
      cj[ss] = jb * 16 + ss;
    }
#pragma unroll
    for (int st = 1; st < 16; st <<= 1)
#pragma unroll
      for (int ss = 0; ss < 16; ss += 2 * st)
        if (cv[ss + st] > cv[ss]) { cv[ss] = cv[ss + st]; cj[ss] = cj[ss + st]; }
    float v = cv[0];
    int bj = cj[0];
    float ov = __shfl_xor(v, 32);
    int oj = __shfl_xor(bj, 32);
    if (ov > v || (ov == v && oj < bj)) { v = ov; bj = oj; }

    int t = t0 + s;
    float f = pf;
    int tn = (t + 1 < T_LEN) ? t + 1 : t;
    pf = feats[(size_t)tn * KTAGS + i];
    fv = v + f;
    if (jb == 0) bptr[(size_t)t * KTAGS + i] = (unsigned char)bj;
  }
}

// ---------------- K5: compose 32-step backtrace maps ----------------
__global__ __launch_bounds__(64) void vit_compose(
    const unsigned char* __restrict__ bptr, unsigned char* __restrict__ fmap)
{
  const int m = blockIdx.x;
  __shared__ unsigned char B[32 * 32];
  const int tid = threadIdx.x;
  const uint32_t* src = (const uint32_t*)(bptr + (size_t)m * 1024);
  uint32_t* dstw = (uint32_t*)B;
  for (int idx = tid; idx < 256; idx += 64) dstw[idx] = src[idx];
  __syncthreads();
  if (tid < 32) {
    int y = tid;
#pragma unroll
    for (int tt = 31; tt >= 0; --tt) y = B[tt * 32 + y];
    fmap[m * 32 + tid] = (unsigned char)y;
  }
}

// ---------------- K6: boundary walk + parallel expansion ----------------
__global__ __launch_bounds__(256) void vit_backtrace(
    const unsigned char* __restrict__ bptr, const unsigned char* __restrict__ fmap,
    const int* __restrict__ best, float* __restrict__ path_out)
{
  __shared__ unsigned char F[128 * 32];
  __shared__ unsigned char bound[128];
  const int tid = threadIdx.x;
  const uint32_t* src = (const uint32_t*)fmap;
  uint32_t* dstw = (uint32_t*)F;
  for (int idx = tid; idx < 1024; idx += 256) dstw[idx] = src[idx];
  __syncthreads();
  if (tid == 0) {
    int y = best[0];
    bound[127] = (unsigned char)y;
    for (int m = 127; m >= 1; --m) {
      y = F[m * 32 + y];
      bound[m - 1] = (unsigned char)y;
    }
  }
  __syncthreads();
  if (tid < 128) {
    const int m = tid;
    int y = bound[m];
    path_out[m * 32 + 31] = (float)y;
    for (int tt = 30; tt >= 0; --tt) {
      y = bptr[(size_t)(m * 32 + tt + 1) * 32 + y];
      path_out[m * 32 + tt] = (float)y;
    }
  }
}

extern "C" void kernel_launch(void* const* d_in, const int* in_sizes, int n_in,
                              void* d_out, int out_size, void* d_ws, size_t ws_size,
                              hipStream_t stream)
{
  const int* sent    = (const int*)d_in[0];
  const float* embed = (const float*)d_in[1];
  const float* Wih_f = (const float*)d_in[2];
  const float* Whh_f = (const float*)d_in[3];
  const float* b_f   = (const float*)d_in[4];
  const float* Wih_b = (const float*)d_in[5];
  const float* Whh_b = (const float*)d_in[6];
  const float* b_b   = (const float*)d_in[7];
  const float* W_out = (const float*)d_in[8];
  const float* b_out = (const float*)d_in[9];
  const float* trans = (const float*)d_in[10];
  const float* h0    = (const float*)d_in[11];
  const float* c0    = (const float*)d_in[12];

  float* W = (float*)d_ws;
  float* zxF = W;                                    // 16 MB (dead after lstm)
  float* zxB = zxF + (size_t)T_LEN * G4;             // 16 MB
  float* feats = zxB + (size_t)T_LEN * G4;           // 512 KB
  uint32_t* hhF = (uint32_t*)(feats + (size_t)T_LEN * KTAGS);  // 1 MB (int8 h)
  uint32_t* hhB = hhF + (size_t)T_LEN * 64;          // 1 MB
  int* bestIdx = (int*)(hhB + (size_t)T_LEN * 64);
  unsigned char* bptr = (unsigned char*)(bestIdx + 16);  // 128 KB
  unsigned char* fmap = bptr + (size_t)T_LEN * KTAGS;    // 4 KB
  // overlay on dead zxF region: chunk matrices + chunk-boundary fv vectors
  float* Cmat = zxF;                                 // 512 KB
  float* fvs = zxF + NCHUNK * 1024;                  // 129*32 floats

  float* out = (float*)d_out;  // out[0]=path_score, out[1..4096]=path tags

  zx_gemm<<<dim3(T_LEN / 8, 2), 256, 0, stream>>>(sent, embed, Wih_f, b_f, Wih_b, b_b, zxF, zxB);
  lstm_kernel<<<2, 1024, 0, stream>>>(Whh_f, Whh_b, h0, c0, zxF, zxB, hhF, hhB);
  feat_kernel<<<T_LEN / 8, 256, 0, stream>>>(hhF, hhB, W_out, b_out, feats);
  vit_phaseA<<<NCHUNK, 1024, 0, stream>>>(feats, trans, Cmat);
  vit_phaseB<<<1, 64, 0, stream>>>(Cmat, trans, fvs, out, bestIdx);
  vit_phaseC<<<NCHUNK, 64, 0, stream>>>(feats, trans, fvs, bptr);
  vit_compose<<<128, 64, 0, stream>>>(bptr, fmap);
  vit_backtrace<<<1, 256, 0, stream>>>(bptr, fmap, bestIdx, out + 1);
}

// Round 7
// 4167.707 us; speedup vs baseline: 4.2380x; 1.1580x over previous
//
#include <hip/hip_runtime.h>
#include <hip/hip_bf16.h>
#include <cstdint>
#include <cstddef>

// BiLSTM-CRF forward + Viterbi decode, T=4096, E=300, H2=256, K=32.
//   K1 zx_gemm    : zx[t] = Wih @ embed[token] + b (both dirs, batched)
//   K2 lstm_kernel: one CU per direction, 1024 thr, int8 weight-stationary.
//                   R7: 4-way k-split — thread (e, l=tid&3) owns k-slice l of
//                   the 4 gate-rows of elem e, stored in ROTATED order
//                   (s -> row (l+s)&3) so the cross-lane k-reduction is 3
//                   quad-perm DPP int-adds that deliver gate g's total to
//                   lane g directly. LDS h-reads: 4 b128/thread (R6 re-read
//                   all 16 -> 256 b128/CU-step on the shared LDS pipe ~1000cy;
//                   now 64). Gate transcendentals distributed: lane g
//                   computes sigma/tanh of its own gate via tanh(x)=2sig(2x)-1
//                   (uniform code), then 3 DPP movs into lane 0 for c/h.
//   K3 feat_kernel: feats = [hf|hb] @ W_out^T + b_out (unpack int8 h)
//   K4a/b/c       : Viterbi via max-plus chunk composition
//   K5 compose, K6 backtrace: parallel backtrace reconstruction.

#define T_LEN 4096
#define E_DIM 300
#define H2 256
#define G4 1024
#define KTAGS 32
#define START_TAG 30
#define STOP_TAG 31
#define NEGV (-10000.0f)
#define NCHUNK 128
#define CLEN 32

#if defined(__has_builtin)
#if __has_builtin(__builtin_amdgcn_sdot4)
#define HAVE_SDOT4 1
#endif
#endif
#ifndef HAVE_SDOT4
#define HAVE_SDOT4 0
#endif

__device__ __forceinline__ int dot4(int a, int b, int c) {
#if HAVE_SDOT4
  return __builtin_amdgcn_sdot4(a, b, c, false);
#else
  int r = c;
  r += (int)(int8_t)(a) * (int)(int8_t)(b);
  r += (int)(int8_t)(a >> 8) * (int)(int8_t)(b >> 8);
  r += (int)(int8_t)(a >> 16) * (int)(int8_t)(b >> 16);
  r += (int)(int8_t)(a >> 24) * (int)(int8_t)(b >> 24);
  return r;
#endif
}

__device__ __forceinline__ float fast_sigmoid(float x) {
  return __builtin_amdgcn_rcpf(1.0f + __expf(-x));
}
__device__ __forceinline__ float fast_tanh(float x) {
  return 1.0f - 2.0f * __builtin_amdgcn_rcpf(__expf(2.0f * x) + 1.0f);
}

template <int CTRL>
__device__ __forceinline__ float dppmovf(float x) {
  return __int_as_float(
      __builtin_amdgcn_update_dpp(0, __float_as_int(x), CTRL, 0xF, 0xF, true));
}
template <int CTRL>
__device__ __forceinline__ int dppmovi(int x) {
  return __builtin_amdgcn_update_dpp(0, x, CTRL, 0xF, 0xF, true);
}

// ---------------- K1: input projection GEMM ----------------
__global__ __launch_bounds__(256) void zx_gemm(
    const int* __restrict__ sent, const float* __restrict__ embed,
    const float* __restrict__ Wih_f, const float* __restrict__ b_f,
    const float* __restrict__ Wih_b, const float* __restrict__ b_b,
    float* __restrict__ zxF, float* __restrict__ zxB)
{
  const int dir = blockIdx.y;
  const int t0 = blockIdx.x * 8;
  const float* __restrict__ Wih = dir ? Wih_b : Wih_f;
  const float* __restrict__ bias = dir ? b_b : b_f;
  float* __restrict__ zx = dir ? zxB : zxF;

  __shared__ __align__(16) float xs[8 * E_DIM];
  const int tid = threadIdx.x;
  for (int ti = 0; ti < 8; ++ti) {
    int p = t0 + ti;
    int tok = sent[dir ? (T_LEN - 1 - p) : p];
    const float* er = embed + (size_t)tok * E_DIM;
    for (int k = tid; k < E_DIM; k += 256) xs[ti * E_DIM + k] = er[k];
  }
  __syncthreads();

  const int r = tid;
  float acc[4][8];
#pragma unroll
  for (int g = 0; g < 4; ++g) {
    float bv = bias[g * 256 + r];
#pragma unroll
    for (int ti = 0; ti < 8; ++ti) acc[g][ti] = bv;
  }
  const float4* w0p = (const float4*)(Wih + (size_t)(r) * E_DIM);
  const float4* w1p = (const float4*)(Wih + (size_t)(256 + r) * E_DIM);
  const float4* w2p = (const float4*)(Wih + (size_t)(512 + r) * E_DIM);
  const float4* w3p = (const float4*)(Wih + (size_t)(768 + r) * E_DIM);
  for (int k4 = 0; k4 < E_DIM / 4; ++k4) {
    float4 w0 = w0p[k4], w1 = w1p[k4], w2 = w2p[k4], w3 = w3p[k4];
#pragma unroll
    for (int ti = 0; ti < 8; ++ti) {
      float4 x4 = *(const float4*)(xs + ti * E_DIM + k4 * 4);
      acc[0][ti] += w0.x * x4.x + w0.y * x4.y + w0.z * x4.z + w0.w * x4.w;
      acc[1][ti] += w1.x * x4.x + w1.y * x4.y + w1.z * x4.z + w1.w * x4.w;
      acc[2][ti] += w2.x * x4.x + w2.y * x4.y + w2.z * x4.z + w2.w * x4.w;
      acc[3][ti] += w3.x * x4.x + w3.y * x4.y + w3.z * x4.z + w3.w * x4.w;
    }
  }
#pragma unroll
  for (int g = 0; g < 4; ++g)
#pragma unroll
    for (int ti = 0; ti < 8; ++ti)
      zx[(size_t)(t0 + ti) * G4 + g * 256 + r] = acc[g][ti];
}

// ---------------- K2: int8 weight-stationary LSTM (k-split) ----------------
__global__ __launch_bounds__(1024, 4) void lstm_kernel(
    const float* __restrict__ Whh_f, const float* __restrict__ Whh_b,
    const float* __restrict__ h0, const float* __restrict__ c0,
    const float* __restrict__ zxF, const float* __restrict__ zxB,
    uint32_t* __restrict__ hhF, uint32_t* __restrict__ hhB)
{
  const int d = blockIdx.x;
  const float* __restrict__ Whh = d ? Whh_b : Whh_f;
  const float* __restrict__ zxd = d ? zxB : zxF;
  uint32_t* __restrict__ hh = d ? hhB : hhF;

  const int tid = threadIdx.x;
  const int l = tid & 3;   // k-slice AND my gate
  const int e = tid >> 2;  // h element 0..255

  __shared__ __align__(16) uint32_t hQA[64];  // int8-packed h, 256 B
  __shared__ __align__(16) uint32_t hQB[64];

  // ---- one-time: quantize 4 rotated gate-rows, slice l -> 64 dwords ----
  // s -> global row ((l+s)&3)*256 + e, dwords [l*16, l*16+16)
  int wq[64];
  float sw[4];
#pragma unroll
  for (int s = 0; s < 4; ++s) {
    int r = (l + s) & 3;
    const float4* Wr = (const float4*)(Whh + (size_t)(r * 256 + e) * H2);
    float amax = 1e-12f;
    for (int i = 0; i < 64; ++i) {  // full-row scan: scale consistent across slices
      float4 v = Wr[i];
      amax = fmaxf(amax, fmaxf(fmaxf(fabsf(v.x), fabsf(v.y)),
                               fmaxf(fabsf(v.z), fabsf(v.w))));
    }
    const float winv = 127.f / amax;
    sw[s] = amax / 127.f;
    for (int i = 0; i < 16; ++i) {
      float4 v = Wr[l * 16 + i];
      int b0 = ((int)rintf(v.x * winv)) & 255;
      int b1 = ((int)rintf(v.y * winv)) & 255;
      int b2 = ((int)rintf(v.z * winv)) & 255;
      int b3 = ((int)rintf(v.w * winv)) & 255;
      wq[s * 16 + i] = b0 | (b1 << 8) | (b2 << 16) | (b3 << 24);
    }
  }

  // ---- h0 scale (redundant scan) + seed ----
  float h0max = 1e-12f;
  const float4* H0 = (const float4*)(h0 + d * H2);
  for (int i = 0; i < 64; ++i) {
    float4 v = H0[i];
    h0max = fmaxf(h0max, fmaxf(fmaxf(fabsf(v.x), fabsf(v.y)),
                               fmaxf(fabsf(v.z), fabsf(v.w))));
  }
  if (tid < 64) {
    float inv0 = 127.f / h0max;
    float4 v = H0[tid];
    int b0 = ((int)rintf(v.x * inv0)) & 255;
    int b1 = ((int)rintf(v.y * inv0)) & 255;
    int b2 = ((int)rintf(v.z * inv0)) & 255;
    int b3 = ((int)rintf(v.w * inv0)) & 255;
    hQA[tid] = (uint32_t)(b0 | (b1 << 8) | (b2 << 16) | (b3 << 24));
  }

  // my row total lands in lane l -> row l (s=0); scale = sw[0] * h-scale
  const float scale_first = sw[0] * (h0max / 127.f);
  const float scale_rest = sw[0] * (1.f / 127.f);

  float c = c0[d * H2 + e];  // used only in lane l==0

  const float* zp = zxd + l * 256 + e;  // my gate's zx stream
  float zcur = *zp;
  uint32_t* hp = hh + tid;  // tid<64 stores h history
  __syncthreads();

  auto step = [&](const uint32_t* hin, uint32_t* hout, float scale) {
    float znext = zp[G4];  // prefetch t+1 (last step overreads into ws — safe)

    // my k-slice of h: 4 b128 broadcast-group reads
    uint32_t hd[16];
#pragma unroll
    for (int cc = 0; cc < 4; ++cc)
      *(uint4*)(hd + 4 * cc) = *((const uint4*)hin + l * 4 + cc);

    // 4 rotated rows x 16 sdot4
    int acc0 = 0, acc1 = 0, acc2 = 0, acc3 = 0;
#pragma unroll
    for (int i = 0; i < 16; ++i) {
      acc0 = dot4(wq[i], hd[i], acc0);
      acc1 = dot4(wq[16 + i], hd[i], acc1);
      acc2 = dot4(wq[32 + i], hd[i], acc2);
      acc3 = dot4(wq[48 + i], hd[i], acc3);
    }
    // rotate-reduce: lane g receives row-g partials from lanes g-1,g-2,g-3
    int tot = acc0;
    tot += dppmovi<0x93>(acc1);  // shift-up-1: sel[i]=i-1
    tot += dppmovi<0x4E>(acc2);  // shift-up-2
    tot += dppmovi<0x39>(acc3);  // shift-up-3
    float z = (float)tot * scale + zcur;

    // distributed gate function: lane 2 needs tanh = 2*sigmoid(2x)-1
    float x = (l == 2) ? (z + z) : z;
    float sg = fast_sigmoid(x);
    float y = (l == 2) ? (sg + sg - 1.f) : sg;

    // gather f,g,o into lane 0 (i-gate lane)
    float pf = dppmovf<0xB1>(y);  // lane0 <- lane1  sigmoid(zf)
    float pg = dppmovf<0x4E>(y);  // lane0 <- lane2  tanh(zg)
    float po = dppmovf<0x1B>(y);  // lane0 <- lane3  sigmoid(zo)
    if (l == 0) {
      c = pf * c + y * pg;
      float hv = po * fast_tanh(c);
      int q = (int)rintf(hv * 127.f);  // |hv|<1
      ((unsigned char*)hout)[e] = (unsigned char)q;
    }
    zcur = znext;
    zp += G4;
    // barrier WITHOUT vmcnt drain: LDS ordering only; zx prefetch stays in flight
    asm volatile("s_waitcnt lgkmcnt(0)\n\ts_barrier" ::: "memory");
    if (tid < 64) *hp = hout[tid];  // int8 h history
    hp += 64;
  };

  step(hQA, hQB, scale_first);
  step(hQB, hQA, scale_rest);
  for (int t = 2; t < T_LEN; t += 2) {
    step(hQA, hQB, scale_rest);
    step(hQB, hQA, scale_rest);
  }
}

// ---------------- K3: feats = [hf|hb] @ W_out^T + b_out ----------------
__global__ __launch_bounds__(256) void feat_kernel(
    const uint32_t* __restrict__ hhF, const uint32_t* __restrict__ hhB,
    const float* __restrict__ W_out, const float* __restrict__ b_out,
    float* __restrict__ feats)
{
  const int p0 = blockIdx.x * 8;
  const int tid = threadIdx.x;
  __shared__ float hs[8 * 520];
#define HIDX(pos, k) ((pos) * 520 + (k) + ((k) >> 6))
  const float s = 1.f / 127.f;
  for (int idx = tid; idx < 512; idx += 256) {  // 8 pos x 64 dwords
    int pos = idx >> 6, dw = idx & 63;
    uint32_t vf = hhF[(size_t)(p0 + pos) * 64 + dw];
    uint32_t vb = hhB[(size_t)(T_LEN - 1 - (p0 + pos)) * 64 + dw];
    int k = dw * 4;
    hs[HIDX(pos, k + 0)] = (float)(int8_t)(vf) * s;
    hs[HIDX(pos, k + 1)] = (float)(int8_t)(vf >> 8) * s;
    hs[HIDX(pos, k + 2)] = (float)(int8_t)(vf >> 16) * s;
    hs[HIDX(pos, k + 3)] = (float)(int8_t)(vf >> 24) * s;
    int kb = 256 + k;
    hs[HIDX(pos, kb + 0)] = (float)(int8_t)(vb) * s;
    hs[HIDX(pos, kb + 1)] = (float)(int8_t)(vb >> 8) * s;
    hs[HIDX(pos, kb + 2)] = (float)(int8_t)(vb >> 16) * s;
    hs[HIDX(pos, kb + 3)] = (float)(int8_t)(vb >> 24) * s;
  }
  __syncthreads();

  const int tag = tid >> 3;
  const int kc = tid & 7;
  float4 w4[16];
  const float4* wp = (const float4*)(W_out + tag * 512 + kc * 64);
#pragma unroll
  for (int i = 0; i < 16; ++i) w4[i] = wp[i];
  const float bo = b_out[tag];

#pragma unroll
  for (int pos = 0; pos < 8; ++pos) {
    const float* hpp = hs + pos * 520 + kc * 64 + kc;
    float a = 0.f;
#pragma unroll
    for (int i = 0; i < 16; ++i) {
      float4 w = w4[i];
      a += w.x * hpp[i * 4] + w.y * hpp[i * 4 + 1] + w.z * hpp[i * 4 + 2] + w.w * hpp[i * 4 + 3];
    }
    a += __shfl_xor(a, 1);
    a += __shfl_xor(a, 2);
    a += __shfl_xor(a, 4);
    if (kc == 0) feats[(size_t)(p0 + pos) * KTAGS + tag] = a + bo;
  }
}

// ---------------- K4a: parallel chunk transfer matrices ----------------
__global__ __launch_bounds__(1024) void vit_phaseA(
    const float* __restrict__ feats, const float* __restrict__ trans,
    float* __restrict__ Cmat)
{
  const int c = blockIdx.x;
  const int tid = threadIdx.x;
  const int i = tid >> 5, j = tid & 31;
  const int t0 = c * CLEN;

  float Trow[32];
#pragma unroll
  for (int k = 0; k < 32; ++k) Trow[k] = trans[i * 32 + k];

  __shared__ float Ca[1024], Cb[1024];
  Ca[tid] = Trow[j] + feats[(size_t)t0 * KTAGS + i];
  __syncthreads();

  float* cur = Ca;
  float* nxt = Cb;
  for (int s = 1; s < CLEN; ++s) {
    float fi = feats[(size_t)(t0 + s) * KTAGS + i];
    float m = Trow[0] + cur[j];
#pragma unroll
    for (int k = 1; k < 32; ++k) m = fmaxf(m, Trow[k] + cur[k * 32 + j]);
    nxt[tid] = m + fi;
    __syncthreads();
    float* tmp = cur; cur = nxt; nxt = tmp;
  }
  Cmat[(size_t)c * 1024 + tid] = cur[tid];
}

// ---------------- K4b: sequential chunk-level pass (tiny) ----------------
__global__ __launch_bounds__(64) void vit_phaseB(
    const float* __restrict__ Cmat, const float* __restrict__ trans,
    float* __restrict__ fvs, float* __restrict__ score_out,
    int* __restrict__ best_out)
{
  const int ln = threadIdx.x;
  const int i = ln & 31;
  float fv = (i == START_TAG) ? 0.0f : NEGV;
  if (ln < 32) fvs[i] = fv;

  for (int c = 0; c < NCHUNK; ++c) {
    const float* Crow = Cmat + (size_t)c * 1024 + i * 32;
    float cr[32];
#pragma unroll
    for (int w = 0; w < 8; ++w) *(float4*)(cr + 4 * w) = *(const float4*)(Crow + 4 * w);
    float m = cr[0] + __shfl(fv, 0);
#pragma unroll
    for (int jj = 1; jj < 32; ++jj) m = fmaxf(m, cr[jj] + __shfl(fv, jj));
    fv = m;
    if (ln < 32) fvs[(c + 1) * 32 + i] = fv;
  }

  float v = fv + trans[STOP_TAG * 32 + i];
  int bi = i;
#pragma unroll
  for (int m = 1; m < 32; m <<= 1) {
    float ov = __shfl_xor(v, m);
    int oi = __shfl_xor(bi, m);
    if (ov > v || (ov == v && oi < bi)) { v = ov; bi = oi; }
  }
  if (ln == 0) { score_out[0] = v; best_out[0] = bi; }
}

// ---------------- K4c: parallel per-chunk bptr regeneration ----------------
__global__ __launch_bounds__(64) void vit_phaseC(
    const float* __restrict__ feats, const float* __restrict__ trans,
    const float* __restrict__ fvs, unsigned char* __restrict__ bptr)
{
  const int c = blockIdx.x;
  const int ln = threadIdx.x;
  const int i = ln & 31;
  const int jb = ln >> 5;
  const int t0 = c * CLEN;

  float Tj[16];
#pragma unroll
  for (int s = 0; s < 16; ++s) Tj[s] = trans[i * 32 + jb * 16 + s];

  float fv = fvs[c * 32 + i];
  float pf = feats[(size_t)t0 * KTAGS + i];

  for (int s = 0; s < CLEN; ++s) {
    float cv[16];
    int cj[16];
#pragma unroll
    for (int ss = 0; ss < 16; ++ss) {
      cv[ss] = __shfl(fv, jb * 16 + ss) + Tj[ss];
      cj[ss] = jb * 16 + ss;
    }
#pragma unroll
    for (int st = 1; st < 16; st <<= 1)
#pragma unroll
      for (int ss = 0; ss < 16; ss += 2 * st)
        if (cv[ss + st] > cv[ss]) { cv[ss] = cv[ss + st]; cj[ss] = cj[ss + st]; }
    float v = cv[0];
    int bj = cj[0];
    float ov = __shfl_xor(v, 32);
    int oj = __shfl_xor(bj, 32);
    if (ov > v || (ov == v && oj < bj)) { v = ov; bj = oj; }

    int t = t0 + s;
    float f = pf;
    int tn = (t + 1 < T_LEN) ? t + 1 : t;
    pf = feats[(size_t)tn * KTAGS + i];
    fv = v + f;
    if (jb == 0) bptr[(size_t)t * KTAGS + i] = (unsigned char)bj;
  }
}

// ---------------- K5: compose 32-step backtrace maps ----------------
__global__ __launch_bounds__(64) void vit_compose(
    const unsigned char* __restrict__ bptr, unsigned char* __restrict__ fmap)
{
  const int m = blockIdx.x;
  __shared__ unsigned char B[32 * 32];
  const int tid = threadIdx.x;
  const uint32_t* src = (const uint32_t*)(bptr + (size_t)m * 1024);
  uint32_t* dstw = (uint32_t*)B;
  for (int idx = tid; idx < 256; idx += 64) dstw[idx] = src[idx];
  __syncthreads();
  if (tid < 32) {
    int y = tid;
#pragma unroll
    for (int tt = 31; tt >= 0; --tt) y = B[tt * 32 + y];
    fmap[m * 32 + tid] = (unsigned char)y;
  }
}

// ---------------- K6: boundary walk + parallel expansion ----------------
__global__ __launch_bounds__(256) void vit_backtrace(
    const unsigned char* __restrict__ bptr, const unsigned char* __restrict__ fmap,
    const int* __restrict__ best, float* __restrict__ path_out)
{
  __shared__ unsigned char F[128 * 32];
  __shared__ unsigned char bound[128];
  const int tid = threadIdx.x;
  const uint32_t* src = (const uint32_t*)fmap;
  uint32_t* dstw = (uint32_t*)F;
  for (int idx = tid; idx < 1024; idx += 256) dstw[idx] = src[idx];
  __syncthreads();
  if (tid == 0) {
    int y = best[0];
    bound[127] = (unsigned char)y;
    for (int m = 127; m >= 1; --m) {
      y = F[m * 32 + y];
      bound[m - 1] = (unsigned char)y;
    }
  }
  __syncthreads();
  if (tid < 128) {
    const int m = tid;
    int y = bound[m];
    path_out[m * 32 + 31] = (float)y;
    for (int tt = 30; tt >= 0; --tt) {
      y = bptr[(size_t)(m * 32 + tt + 1) * 32 + y];
      path_out[m * 32 + tt] = (float)y;
    }
  }
}

extern "C" void kernel_launch(void* const* d_in, const int* in_sizes, int n_in,
                              void* d_out, int out_size, void* d_ws, size_t ws_size,
                              hipStream_t stream)
{
  const int* sent    = (const int*)d_in[0];
  const float* embed = (const float*)d_in[1];
  const float* Wih_f = (const float*)d_in[2];
  const float* Whh_f = (const float*)d_in[3];
  const float* b_f   = (const float*)d_in[4];
  const float* Wih_b = (const float*)d_in[5];
  const float* Whh_b = (const float*)d_in[6];
  const float* b_b   = (const float*)d_in[7];
  const float* W_out = (const float*)d_in[8];
  const float* b_out = (const float*)d_in[9];
  const float* trans = (const float*)d_in[10];
  const float* h0    = (const float*)d_in[11];
  const float* c0    = (const float*)d_in[12];

  float* W = (float*)d_ws;
  float* zxF = W;                                    // 16 MB (dead after lstm)
  float* zxB = zxF + (size_t)T_LEN * G4;             // 16 MB
  float* feats = zxB + (size_t)T_LEN * G4;           // 512 KB
  uint32_t* hhF = (uint32_t*)(feats + (size_t)T_LEN * KTAGS);  // 1 MB (int8 h)
  uint32_t* hhB = hhF + (size_t)T_LEN * 64;          // 1 MB
  int* bestIdx = (int*)(hhB + (size_t)T_LEN * 64);
  unsigned char* bptr = (unsigned char*)(bestIdx + 16);  // 128 KB
  unsigned char* fmap = bptr + (size_t)T_LEN * KTAGS;    // 4 KB
  float* Cmat = zxF;                                 // overlay, 512 KB
  float* fvs = zxF + NCHUNK * 1024;                  // 129*32 floats

  float* out = (float*)d_out;  // out[0]=path_score, out[1..4096]=path tags

  zx_gemm<<<dim3(T_LEN / 8, 2), 256, 0, stream>>>(sent, embed, Wih_f, b_f, Wih_b, b_b, zxF, zxB);
  lstm_kernel<<<2, 1024, 0, stream>>>(Whh_f, Whh_b, h0, c0, zxF, zxB, hhF, hhB);
  feat_kernel<<<T_LEN / 8, 256, 0, stream>>>(hhF, hhB, W_out, b_out, feats);
  vit_phaseA<<<NCHUNK, 1024, 0, stream>>>(feats, trans, Cmat);
  vit_phaseB<<<1, 64, 0, stream>>>(Cmat, trans, fvs, out, bestIdx);
  vit_phaseC<<<NCHUNK, 64, 0, stream>>>(feats, trans, fvs, bptr);
  vit_compose<<<128, 64, 0, stream>>>(bptr, fmap);
  vit_backtrace<<<1, 256, 0, stream>>>(bptr, fmap, bestIdx, out + 1);
}